// Round 1
// baseline (206.987 us; speedup 1.0000x reference)
//
#include <hip/hip_runtime.h>
#include <hip/hip_fp16.h>

#define NBINS 255
#define NPAIRS 32
#define BIGF 3.0e38f

// ws layout (float index):
//   [0     ,16384) : E    [64][256] fp32, tail BIGF
//   [16384 ,32768) : PE   [64][256]
//   [32768 ,36864) : M4E  [64][16] float4 {e[4j+3]} j=4t+c  (idx>=255 -> BIGF)
//   [36864 ,40960) : M4P
//   [40960 ,41984) : CU16 [64][16] coarse e[16j+15], j=15 pad BIGF
//   [41984 ,43008) : CP16
//   [43008 ,51200) : W16g [64][256] fp16 PRE-SHIFTED (8192 floats of storage)
//   byte 204800 .. : T16  [32][256][256] fp16 PRE-SHIFTED (needs ws >= 4399104 B)

__global__ void ebm_prep(const float* __restrict__ edges,
                         const float* __restrict__ pair_edges,
                         const float* __restrict__ w,
                         float* __restrict__ ws) {
    int tid = blockIdx.x * blockDim.x + threadIdx.x;  // 16384 threads
    int f = tid >> 8, j = tid & 255;
    float* E  = ws;
    float* PE = ws + 16384;
    float* ME = ws + 32768;
    float* MP = ws + 36864;
    float* CU = ws + 40960;
    float* CP = ws + 41984;
    __half* W = (__half*)(ws + 43008);
    E[tid]  = (j < NBINS) ? edges[f * NBINS + j]      : BIGF;
    PE[tid] = (j < NBINS) ? pair_edges[f * NBINS + j] : BIGF;
    int src = (j < 255) ? j + 1 : 0;
    W[tid]  = __float2half(w[f * 256 + src]);
    if (j < 64) {
        int idx = 4 * j + 3;   // j=4t+c -> e[16t+4c+3]
        ME[f * 64 + j] = (idx < NBINS) ? edges[f * NBINS + idx]      : BIGF;
        MP[f * 64 + j] = (idx < NBINS) ? pair_edges[f * NBINS + idx] : BIGF;
    }
    if (j < 16) {
        CU[f * 16 + j] = (j < 15) ? edges[f * NBINS + 16 * j + 15]      : BIGF;
        CP[f * 16 + j] = (j < 15) ? pair_edges[f * NBINS + 16 * j + 15] : BIGF;
    }
}

__global__ void ebm_prep_tables(const float* __restrict__ tables,
                                unsigned short* __restrict__ o) {
    int i = blockIdx.x * blockDim.x + threadIdx.x;    // 2097152 threads
    int b = i & 255, a = (i >> 8) & 255, p = i >> 16;
    int ra = (a < 255) ? a + 1 : 0;
    int rb = (b < 255) ? b + 1 : 0;
    o[i] = __half_as_ushort(__float2half(tables[(p << 16) + (ra << 8) + rb]));
}

// uniform 16-way register select: s is wave-uniform -> 15 v_cndmask w/ scalar masks
__device__ __forceinline__ unsigned pick16(const unsigned* pw, int s) {
    unsigned v01 = (s & 1) ? pw[1]  : pw[0];
    unsigned v23 = (s & 1) ? pw[3]  : pw[2];
    unsigned v45 = (s & 1) ? pw[5]  : pw[4];
    unsigned v67 = (s & 1) ? pw[7]  : pw[6];
    unsigned v89 = (s & 1) ? pw[9]  : pw[8];
    unsigned vab = (s & 1) ? pw[11] : pw[10];
    unsigned vcd = (s & 1) ? pw[13] : pw[12];
    unsigned vef = (s & 1) ? pw[15] : pw[14];
    unsigned w0 = (s & 2) ? v23 : v01;
    unsigned w1 = (s & 2) ? v67 : v45;
    unsigned w2 = (s & 2) ? vab : v89;
    unsigned w3 = (s & 2) ? vef : vcd;
    unsigned u0 = (s & 4) ? w1 : w0;
    unsigned u1 = (s & 4) ? w3 : w2;
    return (s & 8) ? u1 : u0;
}

// v2: 2 threads per row (features split 0..31 / 32..63 by WAVE, so the half
// index is wave-uniform and coarse-table reads stay s_loads). 524288 threads,
// 512 blocks x 1024. LDS cut to exactly 80 KiB (unary fine+mid only) so
// 2 blocks/CU fit -> 32 waves/CU (was 16). Pair mid/fine tables are read from
// the hot 80 KB ws region through L1/L2 (mid row = 4 lines/wave). Partner
// halves exchange packed pair-bin words + partial acc through LDS scratch
// aliased onto sE after the main loop; pair gathers split 16/16.
__global__ __launch_bounds__(1024, 8) void ebm_main(
    const float* __restrict__ x,
    const int*   __restrict__ pairs,
    const float* __restrict__ tables_f32,
    const float* __restrict__ bias,
    const float* __restrict__ ws,
    const __half* __restrict__ T16,
    int useT16,
    float*       __restrict__ out) {

    // exactly 80 KiB -> 2 blocks/CU
    __shared__ float  sE[16384];    // unary fine [64][256]
    __shared__ float4 sME[1024];    // unary mid  [64][16]

    int tid = threadIdx.x;
    {
        const float4* w4 = (const float4*)ws;
        float4* dE = (float4*)sE;
        for (int i = tid; i < 4096; i += 1024) dE[i] = w4[i];
        sME[tid] = w4[8192 + tid];
    }
    const float*  CU  = ws + 40960;
    const float*  CP  = ws + 41984;
    const __half* Wg  = (const __half*)(ws + 43008);
    const float4* PE4 = (const float4*)(ws + 16384);   // pair fine [64][64]f4 (global, L1/L2-hot)
    const float4* MP4 = (const float4*)(ws + 36864);   // pair mid  [64][16]f4 (global)
    float bias0 = bias[0];

    __syncthreads();

    int wv   = tid >> 6;           // 0..15
    int lane = tid & 63;
    int half = wv >> 3;            // wave-uniform by construction...
    int halfU = __builtin_amdgcn_readfirstlane(half);  // ...force SGPR so row indices stay scalar
    int rowl = (wv & 7) * 64 + lane;          // 0..511 local row
    int row  = blockIdx.x * 512 + rowl;

    const float4* x4  = (const float4*)x + row * 16 + halfU * 8;
    const float4* sE4 = (const float4*)sE;

    float acc = 0.f;
    unsigned pw[8];

    float4 xg = x4[0];
#pragma unroll
    for (int g = 0; g < 8; ++g) {
        int fb = (halfU * 8 + g) * 4;         // global feature base, wave-uniform
        float4 xnext = xg;
        if (g < 7) xnext = x4[g + 1];
        float xf[4] = {xg.x, xg.y, xg.z, xg.w};

        // ---- unary: coarse (SGPR compares) ----
        int t[4];
#pragma unroll
        for (int j = 0; j < 4; ++j) {
            const float* cu = CU + (fb + j) * 16;   // uniform -> s_load
            int tt = 0;
#pragma unroll
            for (int k = 0; k < 15; ++k) tt += (xf[j] >= cu[k]);
            t[j] = tt;
        }
        // ---- pair: coarse ----
        int t2[4];
#pragma unroll
        for (int j = 0; j < 4; ++j) {
            const float* cp = CP + (fb + j) * 16;
            int tt = 0;
#pragma unroll
            for (int k = 0; k < 15; ++k) tt += (xf[j] >= cp[k]);
            t2[j] = tt;
        }
        // ---- mids: unary from LDS, pair from global (4 lines/wave, L1-hot) ----
        float4 mu[4], mp[4];
#pragma unroll
        for (int j = 0; j < 4; ++j) mu[j] = sME[(fb + j) * 16 + t[j]];
#pragma unroll
        for (int j = 0; j < 4; ++j) mp[j] = MP4[(fb + j) * 16 + t2[j]];
        // ---- fine loads: unary LDS, pair global ----
        int lo[4], lo2[4];
        float4 fu[4], fp[4];
#pragma unroll
        for (int j = 0; j < 4; ++j) {
            int m = (xf[j] >= mu[j].x) + (xf[j] >= mu[j].y) + (xf[j] >= mu[j].z);
            lo[j] = 4 * t[j] + m;
            fu[j] = sE4[(fb + j) * 64 + lo[j]];
        }
#pragma unroll
        for (int j = 0; j < 4; ++j) {
            int m = (xf[j] >= mp[j].x) + (xf[j] >= mp[j].y) + (xf[j] >= mp[j].z);
            lo2[j] = 4 * t2[j] + m;
            fp[j] = PE4[(fb + j) * 64 + lo2[j]];
        }
        // ---- unary consume -> W gather (global fp16, <=8 lines/wave) ----
#pragma unroll
        for (int j = 0; j < 4; ++j) {
            int c = 4 * lo[j] + (xf[j] >= fu[j].x) + (xf[j] >= fu[j].y) +
                    (xf[j] >= fu[j].z) + (xf[j] >= fu[j].w);
            acc += __half2float(Wg[(fb + j) * 256 + c]);
        }
        // ---- pair consume -> pack 8-bit ----
        unsigned pword = 0;
#pragma unroll
        for (int j = 0; j < 4; ++j) {
            int c2 = 4 * lo2[j] + (xf[j] >= fp[j].x) + (xf[j] >= fp[j].y) +
                     (xf[j] >= fp[j].z) + (xf[j] >= fp[j].w);
            pword |= (unsigned)c2 << (8 * j);
        }
        pw[g] = pword;
        xg = xnext;
    }

    // ---- exchange pair words with the partner half via LDS scratch ----
    // scratch aliases sE (tables no longer needed); layout [i][half][rowl]
    // -> consecutive lanes hit consecutive banks, conflict-free.
    unsigned* scr  = (unsigned*)sE;          // 16*512 u32 = 32 KiB used
    float*    accS = (float*)sME;            // 2*512 f32 = 4 KiB used
    __syncthreads();                          // all sE/sME table reads done
#pragma unroll
    for (int i = 0; i < 8; ++i)
        scr[(i * 2 + halfU) * 512 + rowl] = pw[i];
    __syncthreads();                          // pw published
    unsigned oth[8];
#pragma unroll
    for (int i = 0; i < 8; ++i)
        oth[i] = scr[(i * 2 + (1 - halfU)) * 512 + rowl];
    unsigned pwAll[16];                       // static indices only (no scratch spill)
#pragma unroll
    for (int i = 0; i < 8; ++i) {
        pwAll[i]     = halfU ? oth[i] : pw[i];
        pwAll[8 + i] = halfU ? pw[i]  : oth[i];
    }

    // ---- pair table gathers: 16 per thread (split between partners) ----
    int pbase = halfU * 16;
    if (useT16) {
#pragma unroll
        for (int q = 0; q < 16; ++q) {
            int p = pbase + q;                          // uniform
            int a = pairs[2 * p], b = pairs[2 * p + 1]; // uniform
            unsigned wa = pick16(pwAll, a >> 2);
            unsigned wb = pick16(pwAll, b >> 2);
            int li = (wa >> ((a & 3) * 8)) & 255;
            int ri = (wb >> ((b & 3) * 8)) & 255;
            acc += __half2float(T16[(p << 16) + (li << 8) + ri]);
        }
    } else {
#pragma unroll
        for (int q = 0; q < 16; ++q) {
            int p = pbase + q;
            int a = pairs[2 * p], b = pairs[2 * p + 1];
            unsigned wa = pick16(pwAll, a >> 2);
            unsigned wb = pick16(pwAll, b >> 2);
            int li = (wa >> ((a & 3) * 8)) & 255;
            int ri = (wb >> ((b & 3) * 8)) & 255;
            int lb = (li < 255) ? li + 1 : 0;
            int rb = (ri < 255) ? ri + 1 : 0;
            acc += tables_f32[(p << 16) + (lb << 8) + rb];
        }
    }

    // ---- combine halves, sigmoid, store (waves 0..7 write 64 contiguous rows) ----
    accS[halfU * 512 + rowl] = acc;
    __syncthreads();
    if (halfU == 0) {
        float tot = acc + accS[512 + rowl];
        out[row] = 1.0f / (1.0f + __expf(-(tot + bias0)));
    }
}

extern "C" void kernel_launch(void* const* d_in, const int* in_sizes, int n_in,
                              void* d_out, int out_size, void* d_ws, size_t ws_size,
                              hipStream_t stream) {
    const float* x          = (const float*)d_in[0];
    const float* edges      = (const float*)d_in[1];
    const float* w          = (const float*)d_in[2];
    const float* pair_edges = (const float*)d_in[3];
    const int*   pairs      = (const int*)d_in[4];
    const float* tables     = (const float*)d_in[5];
    const float* bias       = (const float*)d_in[6];
    float* out = (float*)d_out;
    float* ws  = (float*)d_ws;

    int useT16 = (ws_size >= (size_t)4399104) ? 1 : 0;
    __half* T16 = (__half*)((char*)d_ws + 204800);

    ebm_prep<<<64, 256, 0, stream>>>(edges, pair_edges, w, ws);
    if (useT16) {
        ebm_prep_tables<<<2048, 1024, 0, stream>>>(tables, (unsigned short*)T16);
    }
    ebm_main<<<512, 1024, 0, stream>>>(x, pairs, tables, bias, ws, T16, useT16, out);
}

// Round 2
// 192.329 us; speedup vs baseline: 1.0762x; 1.0762x over previous
//
#include <hip/hip_runtime.h>
#include <hip/hip_fp16.h>

#define NBINS 255
#define NPAIRS 32
#define BIGF 3.0e38f

// ws layout (float index):
//   [0     ,16384) : E    [64][256] fp32, tail BIGF
//   [16384 ,32768) : PE   [64][256]
//   [32768 ,36864) : M4E  [64][16] float4 {e[4j+3]} j=4t+c  (idx>=255 -> BIGF)
//   [36864 ,40960) : M4P
//   [40960 ,41984) : CU16 [64][16] coarse e[16j+15], j=15 pad BIGF
//   [41984 ,43008) : CP16
//   [43008 ,51200) : W16g [64][256] fp16 PRE-SHIFTED (8192 floats of storage)
//   byte 204800 .. : T16  [32][256][256] fp16 PRE-SHIFTED (needs ws >= 4399104 B)

__global__ void ebm_prep(const float* __restrict__ edges,
                         const float* __restrict__ pair_edges,
                         const float* __restrict__ w,
                         float* __restrict__ ws) {
    int tid = blockIdx.x * blockDim.x + threadIdx.x;  // 16384 threads
    int f = tid >> 8, j = tid & 255;
    float* E  = ws;
    float* PE = ws + 16384;
    float* ME = ws + 32768;
    float* MP = ws + 36864;
    float* CU = ws + 40960;
    float* CP = ws + 41984;
    __half* W = (__half*)(ws + 43008);
    E[tid]  = (j < NBINS) ? edges[f * NBINS + j]      : BIGF;
    PE[tid] = (j < NBINS) ? pair_edges[f * NBINS + j] : BIGF;
    int src = (j < 255) ? j + 1 : 0;
    W[tid]  = __float2half(w[f * 256 + src]);
    if (j < 64) {
        int idx = 4 * j + 3;   // j=4t+c -> e[16t+4c+3]
        ME[f * 64 + j] = (idx < NBINS) ? edges[f * NBINS + idx]      : BIGF;
        MP[f * 64 + j] = (idx < NBINS) ? pair_edges[f * NBINS + idx] : BIGF;
    }
    if (j < 16) {
        CU[f * 16 + j] = (j < 15) ? edges[f * NBINS + 16 * j + 15]      : BIGF;
        CP[f * 16 + j] = (j < 15) ? pair_edges[f * NBINS + 16 * j + 15] : BIGF;
    }
}

__global__ void ebm_prep_tables(const float* __restrict__ tables,
                                unsigned short* __restrict__ o) {
    int i = blockIdx.x * blockDim.x + threadIdx.x;    // 2097152 threads
    int b = i & 255, a = (i >> 8) & 255, p = i >> 16;
    int ra = (a < 255) ? a + 1 : 0;
    int rb = (b < 255) ? b + 1 : 0;
    o[i] = __half_as_ushort(__float2half(tables[(p << 16) + (ra << 8) + rb]));
}

// uniform 16-way register select: s is wave-uniform -> 15 v_cndmask w/ scalar masks
__device__ __forceinline__ unsigned pick16(const unsigned* pw, int s) {
    unsigned v01 = (s & 1) ? pw[1]  : pw[0];
    unsigned v23 = (s & 1) ? pw[3]  : pw[2];
    unsigned v45 = (s & 1) ? pw[5]  : pw[4];
    unsigned v67 = (s & 1) ? pw[7]  : pw[6];
    unsigned v89 = (s & 1) ? pw[9]  : pw[8];
    unsigned vab = (s & 1) ? pw[11] : pw[10];
    unsigned vcd = (s & 1) ? pw[13] : pw[12];
    unsigned vef = (s & 1) ? pw[15] : pw[14];
    unsigned w0 = (s & 2) ? v23 : v01;
    unsigned w1 = (s & 2) ? v67 : v45;
    unsigned w2 = (s & 2) ? vab : v89;
    unsigned w3 = (s & 2) ? vef : vcd;
    unsigned u0 = (s & 4) ? w1 : w0;
    unsigned u1 = (s & 4) ? w3 : w2;
    return (s & 8) ? u1 : u0;
}

// v3: v1 memory plan (all tables LDS, 160 KiB, 1 block/CU) + 8-wide feature
// batching: per step, 16 mid ds_reads in flight, then 16 fine ds_reads, then
// 8 W gathers. Halves the lgkm drain points per row vs v1's 4-wide batches.
// VGPR budget: __launch_bounds__(1024,4) caps at 128 so the 16-wave block fits.
__global__ __launch_bounds__(1024, 4) void ebm_main(
    const float* __restrict__ x,
    const int*   __restrict__ pairs,
    const float* __restrict__ tables_f32,
    const float* __restrict__ bias,
    const float* __restrict__ ws,
    const __half* __restrict__ T16,
    int useT16,
    float*       __restrict__ out) {

    // exactly 160 KiB
    __shared__ float  sE[16384];
    __shared__ float  sPE[16384];
    __shared__ float4 sME[1024];
    __shared__ float4 sMP[1024];

    int tid = threadIdx.x;
    {
        const float4* w4 = (const float4*)ws;
        float4* dE = (float4*)sE;
        float4* dP = (float4*)sPE;
        for (int i = tid; i < 4096; i += 1024) {
            dE[i] = w4[i];
            dP[i] = w4[4096 + i];
        }
        sME[tid] = w4[8192 + tid];
        sMP[tid] = w4[9216 + tid];
    }
    const float*  CU = ws + 40960;
    const float*  CP = ws + 41984;
    const __half* Wg = (const __half*)(ws + 43008);
    float bias0 = bias[0];

    __syncthreads();

    int row = blockIdx.x * 1024 + tid;       // 256 blocks x 1024 threads
    const float4* x4  = (const float4*)x + row * 16;
    const float4* sE4 = (const float4*)sE;
    const float4* sP4 = (const float4*)sPE;

    float acc = 0.f;
    unsigned pw[16];

    float4 xa = x4[0];
    float4 xb = x4[1];
#pragma unroll
    for (int gg = 0; gg < 8; ++gg) {
        int fb = gg * 8;                      // feature base (uniform)
        float4 xan = xa, xbn = xb;
        if (gg < 7) { xan = x4[2 * gg + 2]; xbn = x4[2 * gg + 3]; }
        float xf[8] = {xa.x, xa.y, xa.z, xa.w, xb.x, xb.y, xb.z, xb.w};

        // ---- coarse: unary then pair (SGPR-table compares, pure VALU) ----
        int t[8], t2[8];
#pragma unroll
        for (int j = 0; j < 8; ++j) {
            const float* cu = CU + (fb + j) * 16;   // uniform -> s_load
            int tt = 0;
#pragma unroll
            for (int k = 0; k < 15; ++k) tt += (xf[j] >= cu[k]);
            t[j] = tt;
        }
#pragma unroll
        for (int j = 0; j < 8; ++j) {
            const float* cp = CP + (fb + j) * 16;
            int tt = 0;
#pragma unroll
            for (int k = 0; k < 15; ++k) tt += (xf[j] >= cp[k]);
            t2[j] = tt;
        }
        // ---- mids: 16 ds_read_b128 in flight ----
        float4 mu[8], mp[8];
#pragma unroll
        for (int j = 0; j < 8; ++j) mu[j] = sME[(fb + j) * 16 + t[j]];
#pragma unroll
        for (int j = 0; j < 8; ++j) mp[j] = sMP[(fb + j) * 16 + t2[j]];
        // ---- fines: 16 ds_read_b128 in flight ----
        int lo[8], lo2[8];
        float4 fu[8], fp[8];
#pragma unroll
        for (int j = 0; j < 8; ++j) {
            int m = (xf[j] >= mu[j].x) + (xf[j] >= mu[j].y) + (xf[j] >= mu[j].z);
            lo[j] = 4 * t[j] + m;
            fu[j] = sE4[(fb + j) * 64 + lo[j]];
        }
#pragma unroll
        for (int j = 0; j < 8; ++j) {
            int m = (xf[j] >= mp[j].x) + (xf[j] >= mp[j].y) + (xf[j] >= mp[j].z);
            lo2[j] = 4 * t2[j] + m;
            fp[j] = sP4[(fb + j) * 64 + lo2[j]];
        }
        // ---- unary consume -> W gather (global fp16, latency-tolerant) ----
#pragma unroll
        for (int j = 0; j < 8; ++j) {
            int c = 4 * lo[j] + (xf[j] >= fu[j].x) + (xf[j] >= fu[j].y) +
                    (xf[j] >= fu[j].z) + (xf[j] >= fu[j].w);
            acc += __half2float(Wg[(fb + j) * 256 + c]);
        }
        // ---- pair consume -> pack two 4x8-bit words ----
        unsigned p0 = 0, p1 = 0;
#pragma unroll
        for (int j = 0; j < 4; ++j) {
            int c2 = 4 * lo2[j] + (xf[j] >= fp[j].x) + (xf[j] >= fp[j].y) +
                     (xf[j] >= fp[j].z) + (xf[j] >= fp[j].w);
            p0 |= (unsigned)c2 << (8 * j);
        }
#pragma unroll
        for (int j = 4; j < 8; ++j) {
            int c2 = 4 * lo2[j] + (xf[j] >= fp[j].x) + (xf[j] >= fp[j].y) +
                     (xf[j] >= fp[j].z) + (xf[j] >= fp[j].w);
            p1 |= (unsigned)c2 << (8 * (j - 4));
        }
        pw[2 * gg]     = p0;
        pw[2 * gg + 1] = p1;
        xa = xan; xb = xbn;
    }

    // ---- pair table gathers: per-lane-owned, no exchange ----
    if (useT16) {
#pragma unroll
        for (int p = 0; p < NPAIRS; ++p) {
            int a = pairs[2 * p], b = pairs[2 * p + 1];   // uniform
            unsigned wa = pick16(pw, a >> 2);
            unsigned wb = pick16(pw, b >> 2);
            int li = (wa >> ((a & 3) * 8)) & 255;
            int ri = (wb >> ((b & 3) * 8)) & 255;
            acc += __half2float(T16[(p << 16) + (li << 8) + ri]);
        }
    } else {
#pragma unroll
        for (int p = 0; p < NPAIRS; ++p) {
            int a = pairs[2 * p], b = pairs[2 * p + 1];
            unsigned wa = pick16(pw, a >> 2);
            unsigned wb = pick16(pw, b >> 2);
            int li = (wa >> ((a & 3) * 8)) & 255;
            int ri = (wb >> ((b & 3) * 8)) & 255;
            int lb = (li < 255) ? li + 1 : 0;
            int rb = (ri < 255) ? ri + 1 : 0;
            acc += tables_f32[(p << 16) + (lb << 8) + rb];
        }
    }

    out[row] = 1.0f / (1.0f + __expf(-(acc + bias0)));
}

extern "C" void kernel_launch(void* const* d_in, const int* in_sizes, int n_in,
                              void* d_out, int out_size, void* d_ws, size_t ws_size,
                              hipStream_t stream) {
    const float* x          = (const float*)d_in[0];
    const float* edges      = (const float*)d_in[1];
    const float* w          = (const float*)d_in[2];
    const float* pair_edges = (const float*)d_in[3];
    const int*   pairs      = (const int*)d_in[4];
    const float* tables     = (const float*)d_in[5];
    const float* bias       = (const float*)d_in[6];
    float* out = (float*)d_out;
    float* ws  = (float*)d_ws;

    int useT16 = (ws_size >= (size_t)4399104) ? 1 : 0;
    __half* T16 = (__half*)((char*)d_ws + 204800);

    ebm_prep<<<64, 256, 0, stream>>>(edges, pair_edges, w, ws);
    if (useT16) {
        ebm_prep_tables<<<2048, 1024, 0, stream>>>(tables, (unsigned short*)T16);
    }
    ebm_main<<<256, 1024, 0, stream>>>(x, pairs, tables, bias, ws, T16, useT16, out);
}